// Round 3
// baseline (430.232 us; speedup 1.0000x reference)
//
#include <hip/hip_runtime.h>

#define N_NODES 50000
#define N_EDGES 800000
#define IN_DIM  256
#define OUT_DIM 64

// --- d_ws byte layout (all 16B-aligned) ------------------------------------
#define WS_SUPPORT 0                  // 50000*64*4 = 12,800,000 B
#define WS_COUNTS  12800000           // (N_NODES+1)*4 -> padded 200,064 B
#define WS_OFFSETS 13000064
#define WS_CURSOR  13200128
#define WS_RECS    13400192           // 800000 * 8 B (int2: src, val-bits)
// total ~19.8 MB

// ---------------------------------------------------------------------------
// Kernel 1: support = input @ W.
// 8 rows per wave: W ds_read amortized 8x (32 LDS instr/row instead of 320);
// x comes via wave-uniform global float4 broadcast loads (L1-resident row),
// keeping the LDS pipe free. W layout [k][j]: lanes j=0..63 -> 2-way bank
// alias = free (m136).
// ---------------------------------------------------------------------------
__global__ __launch_bounds__(256) void gcn_gemm(const float* __restrict__ input,
                                                const float* __restrict__ W,
                                                float* __restrict__ support)
{
    __shared__ float Wlds[IN_DIM * OUT_DIM];   // 64 KiB
    {
        const float4* W4  = (const float4*)W;
        float4*       Wl4 = (float4*)Wlds;
        for (int i = threadIdx.x; i < (IN_DIM * OUT_DIM) / 4; i += 256)
            Wl4[i] = W4[i];
    }
    __syncthreads();

    const int lane = threadIdx.x & 63;
    const int gw   = (blockIdx.x * blockDim.x + threadIdx.x) >> 6;
    const int nw   = (gridDim.x * blockDim.x) >> 6;
    const int ngroups = N_NODES / 8;   // 6250, divides exactly

    for (int g = gw; g < ngroups; g += nw) {
        const float* rp = input + (size_t)g * 8 * IN_DIM;
        float acc[8] = {0.f,0.f,0.f,0.f,0.f,0.f,0.f,0.f};
        #pragma unroll 4
        for (int kg = 0; kg < IN_DIM / 4; ++kg) {
            const float w0 = Wlds[(kg * 4 + 0) * OUT_DIM + lane];
            const float w1 = Wlds[(kg * 4 + 1) * OUT_DIM + lane];
            const float w2 = Wlds[(kg * 4 + 2) * OUT_DIM + lane];
            const float w3 = Wlds[(kg * 4 + 3) * OUT_DIM + lane];
            #pragma unroll
            for (int r = 0; r < 8; ++r) {
                const float4 xv = *(const float4*)(rp + r * IN_DIM + kg * 4);
                acc[r] += xv.x * w0 + xv.y * w1 + xv.z * w2 + xv.w * w3;
            }
        }
        float* op = support + (size_t)g * 8 * OUT_DIM;
        #pragma unroll
        for (int r = 0; r < 8; ++r)
            op[r * OUT_DIM + lane] = acc[r];
    }
}

// ---------------------------------------------------------------------------
// Kernel 2: histogram of dst -> counts  (counts pre-zeroed by hipMemsetAsync)
// ---------------------------------------------------------------------------
__global__ __launch_bounds__(256) void gcn_hist(const int* __restrict__ dst,
                                                int* __restrict__ counts)
{
    const int e = blockIdx.x * 256 + threadIdx.x;
    if (e < N_EDGES) atomicAdd(&counts[dst[e]], 1);
}

// ---------------------------------------------------------------------------
// Kernel 3: exclusive prefix sum of counts -> offsets (and cursor copy).
// Single block, 1024 threads, 49 chunks of 1024.
// ---------------------------------------------------------------------------
__global__ __launch_bounds__(1024) void gcn_scan(const int* __restrict__ counts,
                                                 int* __restrict__ offsets,
                                                 int* __restrict__ cursor)
{
    __shared__ int wsum[16];
    __shared__ int wpre[17];
    const int tid  = threadIdx.x;
    const int lane = tid & 63;
    const int wid  = tid >> 6;

    int running = 0;
    for (int chunk = 0; chunk < N_NODES; chunk += 1024) {
        const int i    = chunk + tid;
        const int orig = (i < N_NODES) ? counts[i] : 0;
        int v = orig;
        #pragma unroll
        for (int d = 1; d < 64; d <<= 1) {
            const int u = __shfl_up(v, d);
            if (lane >= d) v += u;
        }
        if (lane == 63) wsum[wid] = v;
        __syncthreads();
        if (tid == 0) {
            int s = 0;
            #pragma unroll
            for (int w = 0; w < 16; ++w) { wpre[w] = s; s += wsum[w]; }
            wpre[16] = s;
        }
        __syncthreads();
        if (i < N_NODES) {
            const int excl = running + wpre[wid] + (v - orig);
            offsets[i] = excl;
            cursor[i]  = excl;
        }
        running += wpre[16];
        __syncthreads();   // protect wsum/wpre reuse next chunk
    }
    if (tid == 0) offsets[N_NODES] = running;   // == N_EDGES
}

// ---------------------------------------------------------------------------
// Kernel 4: bucket edges by dst: recs[pos] = (src, bits(val))
// ---------------------------------------------------------------------------
__global__ __launch_bounds__(256) void gcn_build(const int*   __restrict__ src,
                                                 const int*   __restrict__ dst,
                                                 const float* __restrict__ val,
                                                 int*  __restrict__ cursor,
                                                 int2* __restrict__ recs)
{
    const int e = blockIdx.x * 256 + threadIdx.x;
    if (e < N_EDGES) {
        const int d   = dst[e];
        const int pos = atomicAdd(&cursor[d], 1);
        recs[pos] = make_int2(src[e], __float_as_int(val[e]));
    }
}

// ---------------------------------------------------------------------------
// Kernel 5: per-node gather-accumulate, bias fused. One wave per node;
// lane j = output column j. No atomics: out written exactly once, coalesced.
// ---------------------------------------------------------------------------
__global__ __launch_bounds__(256) void gcn_gather(const float* __restrict__ support,
                                                  const int2*  __restrict__ recs,
                                                  const int*   __restrict__ offsets,
                                                  const float* __restrict__ bias,
                                                  float* __restrict__ out)
{
    const int lane = threadIdx.x & 63;
    const int gw   = (blockIdx.x * blockDim.x + threadIdx.x) >> 6;
    const int nw   = (gridDim.x * blockDim.x) >> 6;
    const float b  = bias[lane];

    for (int n = gw; n < N_NODES; n += nw) {
        const int beg = offsets[n];
        const int end = offsets[n + 1];
        float acc = 0.f;
        for (int i = beg; i < end; ++i) {
            const int2 r = recs[i];   // wave-uniform -> broadcast load
            acc += __int_as_float(r.y) * support[(size_t)r.x * OUT_DIM + lane];
        }
        out[(size_t)n * OUT_DIM + lane] = acc + b;
    }
}

// ---------------------------------------------------------------------------
extern "C" void kernel_launch(void* const* d_in, const int* in_sizes, int n_in,
                              void* d_out, int out_size, void* d_ws, size_t ws_size,
                              hipStream_t stream)
{
    const float* input  = (const float*)d_in[0];
    const float* weight = (const float*)d_in[1];
    const float* bias   = (const float*)d_in[2];
    const float* eval_  = (const float*)d_in[3];
    const int*   esrc   = (const int*)d_in[4];
    const int*   edst   = (const int*)d_in[5];
    float*       out    = (float*)d_out;

    char* ws = (char*)d_ws;
    float* support = (float*)(ws + WS_SUPPORT);
    int*   counts  = (int*)(ws + WS_COUNTS);
    int*   offsets = (int*)(ws + WS_OFFSETS);
    int*   cursor  = (int*)(ws + WS_CURSOR);
    int2*  recs    = (int2*)(ws + WS_RECS);

    hipMemsetAsync(counts, 0, (N_NODES + 1) * sizeof(int), stream);

    // support = X @ W   (independent of the CSR build)
    gcn_gemm<<<1568, 256, 0, stream>>>(input, weight, support);

    // CSR-by-dst build
    gcn_hist<<<(N_EDGES + 255) / 256, 256, 0, stream>>>(edst, counts);
    gcn_scan<<<1, 1024, 0, stream>>>(counts, offsets, cursor);
    gcn_build<<<(N_EDGES + 255) / 256, 256, 0, stream>>>(esrc, edst, eval_, cursor, recs);

    // out[n] = sum_{e: dst=n} val_e * support[src_e] + bias
    gcn_gather<<<12500, 256, 0, stream>>>(support, recs, offsets, bias, out);
}

// Round 4
// 303.946 us; speedup vs baseline: 1.4155x; 1.4155x over previous
//
#include <hip/hip_runtime.h>

#define N_NODES 50000
#define N_EDGES 800000
#define IN_DIM  256
#define OUT_DIM 64
#define NB      196               // ceil(N_NODES/256)

// --- d_ws byte layout (16B-aligned) ----------------------------------------
#define WS_SUPPORT 0              // 12,800,000 B
#define WS_COUNTS  12800000       // 50001 ints -> pad
#define WS_OFFSETS 13000064       // 50001 ints
#define WS_CURSOR  13200128       // 50000 ints
#define WS_BSUM    13400128       // 196 ints
#define WS_BOFF    13400960       // 196 ints
#define WS_RECS    13401792       // 800000 * 8 B
// total ~19.8 MB

// ---------------------------------------------------------------------------
// Kernel 1: support = input @ W.   512-thread blocks -> 16 waves/CU (4/SIMD).
// Each wave: 8 rows. W in LDS [k][j] (lane=col, 2-way bank alias = free).
// Row base goes through readfirstlane so x loads are provably wave-uniform ->
// scalar (s_load) path, keeping VMEM/VALU pipes free for the FMA stream.
// ---------------------------------------------------------------------------
__global__ __launch_bounds__(512) void gcn_gemm(const float* __restrict__ input,
                                                const float* __restrict__ W,
                                                float* __restrict__ support)
{
    __shared__ float Wlds[IN_DIM * OUT_DIM];   // 65536 B
    {
        const float4* W4  = (const float4*)W;
        float4*       Wl4 = (float4*)Wlds;
        for (int i = threadIdx.x; i < (IN_DIM * OUT_DIM) / 4; i += 512)
            Wl4[i] = W4[i];
    }
    __syncthreads();

    const int lane = threadIdx.x & 63;
    const int g = __builtin_amdgcn_readfirstlane(
                      (int)((blockIdx.x * 512 + threadIdx.x) >> 6));
    if (g >= N_NODES / 8) return;   // after barrier; safe

    const float* rp = input + (size_t)g * (8 * IN_DIM);
    float acc[8] = {0.f,0.f,0.f,0.f,0.f,0.f,0.f,0.f};

    #pragma unroll 2
    for (int kg = 0; kg < IN_DIM / 4; ++kg) {
        const float w0 = Wlds[(kg * 4 + 0) * OUT_DIM + lane];
        const float w1 = Wlds[(kg * 4 + 1) * OUT_DIM + lane];
        const float w2 = Wlds[(kg * 4 + 2) * OUT_DIM + lane];
        const float w3 = Wlds[(kg * 4 + 3) * OUT_DIM + lane];
        #pragma unroll
        for (int r = 0; r < 8; ++r) {
            const float4 xv = *(const float4*)(rp + r * IN_DIM + kg * 4);
            acc[r] += xv.x * w0 + xv.y * w1 + xv.z * w2 + xv.w * w3;
        }
    }
    float* op = support + (size_t)g * (8 * OUT_DIM);
    #pragma unroll
    for (int r = 0; r < 8; ++r)
        op[r * OUT_DIM + lane] = acc[r];
}

// ---------------------------------------------------------------------------
// Kernel 2: histogram of dst (counts pre-zeroed by hipMemsetAsync)
// ---------------------------------------------------------------------------
__global__ __launch_bounds__(256) void gcn_hist(const int* __restrict__ dst,
                                                int* __restrict__ counts)
{
    const int e = blockIdx.x * 256 + threadIdx.x;
    if (e < N_EDGES) atomicAdd(&counts[dst[e]], 1);
}

// ---------------------------------------------------------------------------
// Kernels 3a/3b/3c: hierarchical exclusive scan of counts -> offsets, cursor
// ---------------------------------------------------------------------------
__global__ __launch_bounds__(256) void gcn_scanA(const int* __restrict__ counts,
                                                 int* __restrict__ bsum)
{
    __shared__ int wsum[4];
    const int tid = threadIdx.x, lane = tid & 63, wid = tid >> 6;
    const int i = blockIdx.x * 256 + tid;
    int v = (i < N_NODES) ? counts[i] : 0;
    #pragma unroll
    for (int d = 32; d > 0; d >>= 1) v += __shfl_down(v, d);
    if (lane == 0) wsum[wid] = v;
    __syncthreads();
    if (tid == 0) bsum[blockIdx.x] = wsum[0] + wsum[1] + wsum[2] + wsum[3];
}

__global__ __launch_bounds__(256) void gcn_scanB(const int* __restrict__ bsum,
                                                 int* __restrict__ boff)
{
    __shared__ int wsum[4];
    const int tid = threadIdx.x, lane = tid & 63, wid = tid >> 6;
    const int orig = (tid < NB) ? bsum[tid] : 0;
    int v = orig;
    #pragma unroll
    for (int d = 1; d < 64; d <<= 1) {
        const int u = __shfl_up(v, d);
        if (lane >= d) v += u;
    }
    if (lane == 63) wsum[wid] = v;
    __syncthreads();
    int pre = 0;
    for (int w = 0; w < wid; ++w) pre += wsum[w];
    if (tid < NB) boff[tid] = pre + v - orig;
}

__global__ __launch_bounds__(256) void gcn_scanC(const int* __restrict__ counts,
                                                 const int* __restrict__ boff,
                                                 int* __restrict__ offsets,
                                                 int* __restrict__ cursor)
{
    __shared__ int wsum[4];
    const int tid = threadIdx.x, lane = tid & 63, wid = tid >> 6;
    const int i = blockIdx.x * 256 + tid;
    const int orig = (i < N_NODES) ? counts[i] : 0;
    int v = orig;
    #pragma unroll
    for (int d = 1; d < 64; d <<= 1) {
        const int u = __shfl_up(v, d);
        if (lane >= d) v += u;
    }
    if (lane == 63) wsum[wid] = v;
    __syncthreads();
    int pre = boff[blockIdx.x];
    for (int w = 0; w < wid; ++w) pre += wsum[w];
    const int excl = pre + v - orig;
    if (i < N_NODES) { offsets[i] = excl; cursor[i] = excl; }
    if (i == N_NODES - 1) offsets[N_NODES] = excl + orig;
}

// ---------------------------------------------------------------------------
// Kernel 4: bucket edges by dst: recs[pos] = (src, bits(val))
// ---------------------------------------------------------------------------
__global__ __launch_bounds__(256) void gcn_build(const int*   __restrict__ src,
                                                 const int*   __restrict__ dst,
                                                 const float* __restrict__ val,
                                                 int*  __restrict__ cursor,
                                                 int2* __restrict__ recs)
{
    const int e = blockIdx.x * 256 + threadIdx.x;
    if (e < N_EDGES) {
        const int d   = dst[e];
        const int pos = atomicAdd(&cursor[d], 1);
        recs[pos] = make_int2(src[e], __float_as_int(val[e]));
    }
}

// ---------------------------------------------------------------------------
// Kernel 5: per-node gather-accumulate, bias fused, no atomics.
// 1-deep value prefetch: rec[i+1] + its support row load overlap the FMA of
// iteration i, halving the rec->support serial latency chain.
// ---------------------------------------------------------------------------
__global__ __launch_bounds__(256) void gcn_gather(const float* __restrict__ support,
                                                  const int2*  __restrict__ recs,
                                                  const int*   __restrict__ offsets,
                                                  const float* __restrict__ bias,
                                                  float* __restrict__ out)
{
    const int lane = threadIdx.x & 63;
    const int gw   = (blockIdx.x * blockDim.x + threadIdx.x) >> 6;
    const int nw   = (gridDim.x * blockDim.x) >> 6;
    const float b  = bias[lane];

    for (int n = gw; n < N_NODES; n += nw) {
        const int beg = offsets[n];
        const int end = offsets[n + 1];
        float acc = 0.f;
        if (beg < end) {
            int2  r  = recs[beg];
            float sv = support[(size_t)r.x * OUT_DIM + lane];
            float vv = __int_as_float(r.y);
            for (int i = beg; i < end - 1; ++i) {
                const int2  rn  = recs[i + 1];                       // indep load
                const float svn = support[(size_t)rn.x * OUT_DIM + lane];
                acc += vv * sv;
                sv = svn;
                vv = __int_as_float(rn.y);
            }
            acc += vv * sv;
        }
        out[(size_t)n * OUT_DIM + lane] = acc + b;
    }
}

// ---------------------------------------------------------------------------
extern "C" void kernel_launch(void* const* d_in, const int* in_sizes, int n_in,
                              void* d_out, int out_size, void* d_ws, size_t ws_size,
                              hipStream_t stream)
{
    const float* input  = (const float*)d_in[0];
    const float* weight = (const float*)d_in[1];
    const float* bias   = (const float*)d_in[2];
    const float* eval_  = (const float*)d_in[3];
    const int*   esrc   = (const int*)d_in[4];
    const int*   edst   = (const int*)d_in[5];
    float*       out    = (float*)d_out;

    char* ws = (char*)d_ws;
    float* support = (float*)(ws + WS_SUPPORT);
    int*   counts  = (int*)(ws + WS_COUNTS);
    int*   offsets = (int*)(ws + WS_OFFSETS);
    int*   cursor  = (int*)(ws + WS_CURSOR);
    int*   bsum    = (int*)(ws + WS_BSUM);
    int*   boff    = (int*)(ws + WS_BOFF);
    int2*  recs    = (int2*)(ws + WS_RECS);

    hipMemsetAsync(counts, 0, N_NODES * sizeof(int), stream);

    // support = X @ W
    gcn_gemm<<<(N_NODES / 8 + 7) / 8, 512, 0, stream>>>(input, weight, support);

    // CSR-by-dst build
    gcn_hist <<<(N_EDGES + 255) / 256, 256, 0, stream>>>(edst, counts);
    gcn_scanA<<<NB, 256, 0, stream>>>(counts, bsum);
    gcn_scanB<<<1, 256, 0, stream>>>(bsum, boff);
    gcn_scanC<<<NB, 256, 0, stream>>>(counts, boff, offsets, cursor);
    gcn_build<<<(N_EDGES + 255) / 256, 256, 0, stream>>>(esrc, edst, eval_, cursor, recs);

    // out[n] = sum_{e: dst=n} val_e * support[src_e] + bias
    gcn_gather<<<12500, 256, 0, stream>>>(support, recs, offsets, bias, out);
}

// Round 8
// 241.942 us; speedup vs baseline: 1.7782x; 1.2563x over previous
//
#include <hip/hip_runtime.h>

#define N_NODES 50000
#define N_EDGES 800000
#define IN_DIM  256
#define OUT_DIM 64
#define NB      196               // ceil(N_NODES/256)

// --- d_ws byte layout (16B-aligned) ----------------------------------------
#define WS_SUPPORT 0              // 12,800,000 B
#define WS_COUNTS  12800000
#define WS_OFFSETS 13000064
#define WS_CURSOR  13200128
#define WS_BSUM    13400128
#define WS_BOFF    13400960
#define WS_RECS    13401792       // 800000 * 8 B
// total ~19.8 MB

// ---------------------------------------------------------------------------
// Kernel 1: support = input @ W.  Block = 64 rows. lane = row; wave w owns
// cols 16w..16w+15 (acc[16] in VGPRs). X staged per 64-k chunk in LDS with
// rotation slot=(k6+row)&63: staging writes AND compute reads are both 2-way
// bank-aliased = free (m136). X loads: coalesced per-lane float4 (VMEM path,
// full BW). W: wave-uniform address -> scalar s_load (64 KB, L2-resident,
// reused by every block). Per k: 1 ds_read_b32 + 16 FMA -> VALU-bound.
// ---------------------------------------------------------------------------
__global__ __launch_bounds__(256) void gcn_gemm(const float* __restrict__ input,
                                                const float* __restrict__ W,
                                                float* __restrict__ support)
{
    __shared__ float Xs[64][64];   // 16 KiB
    const int tid  = threadIdx.x;
    const int lane = tid & 63;
    const int w    = __builtin_amdgcn_readfirstlane(tid >> 6);  // uniform
    const int r0   = blockIdx.x * 64;

    float acc[16];
    #pragma unroll
    for (int j = 0; j < 16; ++j) acc[j] = 0.f;

    const float* Wb = W + w * 16;   // this wave's 16-col block

    for (int kc = 0; kc < 4; ++kc) {
        // ---- stage rows r0..r0+63, k = kc*64..kc*64+63 (coalesced float4)
        #pragma unroll
        for (int it = 0; it < 4; ++it) {
            const int F  = it * 256 + tid;   // flat float4 idx 0..1023
            const int r  = F >> 4;           // 0..63
            const int k4 = (F & 15) * 4;     // 0,4,...,60
            int rr = r0 + r; if (rr > N_NODES - 1) rr = N_NODES - 1;
            const float4 xv = *(const float4*)(input + (size_t)rr * IN_DIM + kc * 64 + k4);
            Xs[r][(k4 + 0 + r) & 63] = xv.x;     // rotated: 2-way banks
            Xs[r][(k4 + 1 + r) & 63] = xv.y;
            Xs[r][(k4 + 2 + r) & 63] = xv.z;
            Xs[r][(k4 + 3 + r) & 63] = xv.w;
        }
        __syncthreads();
        // ---- compute: per k: 1 LDS read (row=lane) + 16 scalar-W FMAs
        const float* Wk = Wb + (size_t)(kc * 64) * OUT_DIM;
        #pragma unroll 8
        for (int k6 = 0; k6 < 64; ++k6) {
            const float x = Xs[lane][(k6 + lane) & 63];
            const float* wrow = Wk + (size_t)k6 * OUT_DIM;  // uniform -> s_load
            #pragma unroll
            for (int j = 0; j < 16; ++j)
                acc[j] += x * wrow[j];
        }
        __syncthreads();
    }

    const int row = r0 + lane;
    if (row < N_NODES) {
        float* op = support + (size_t)row * OUT_DIM + w * 16;
        #pragma unroll
        for (int j = 0; j < 16; j += 4)
            *(float4*)(op + j) = make_float4(acc[j], acc[j+1], acc[j+2], acc[j+3]);
    }
}

// ---------------------------------------------------------------------------
// Kernel 2: histogram of dst (counts pre-zeroed by hipMemsetAsync)
// ---------------------------------------------------------------------------
__global__ __launch_bounds__(256) void gcn_hist(const int* __restrict__ dst,
                                                int* __restrict__ counts)
{
    const int e = blockIdx.x * 256 + threadIdx.x;
    if (e < N_EDGES) atomicAdd(&counts[dst[e]], 1);
}

// ---------------------------------------------------------------------------
// Kernels 3a/3b/3c: hierarchical exclusive scan of counts -> offsets, cursor
// ---------------------------------------------------------------------------
__global__ __launch_bounds__(256) void gcn_scanA(const int* __restrict__ counts,
                                                 int* __restrict__ bsum)
{
    __shared__ int wsum[4];
    const int tid = threadIdx.x, lane = tid & 63, wid = tid >> 6;
    const int i = blockIdx.x * 256 + tid;
    int v = (i < N_NODES) ? counts[i] : 0;
    #pragma unroll
    for (int d = 32; d > 0; d >>= 1) v += __shfl_down(v, d);
    if (lane == 0) wsum[wid] = v;
    __syncthreads();
    if (tid == 0) bsum[blockIdx.x] = wsum[0] + wsum[1] + wsum[2] + wsum[3];
}

__global__ __launch_bounds__(256) void gcn_scanB(const int* __restrict__ bsum,
                                                 int* __restrict__ boff)
{
    __shared__ int wsum[4];
    const int tid = threadIdx.x, lane = tid & 63, wid = tid >> 6;
    const int orig = (tid < NB) ? bsum[tid] : 0;
    int v = orig;
    #pragma unroll
    for (int d = 1; d < 64; d <<= 1) {
        const int u = __shfl_up(v, d);
        if (lane >= d) v += u;
    }
    if (lane == 63) wsum[wid] = v;
    __syncthreads();
    int pre = 0;
    for (int ww = 0; ww < wid; ++ww) pre += wsum[ww];
    if (tid < NB) boff[tid] = pre + v - orig;
}

__global__ __launch_bounds__(256) void gcn_scanC(const int* __restrict__ counts,
                                                 const int* __restrict__ boff,
                                                 int* __restrict__ offsets,
                                                 int* __restrict__ cursor)
{
    __shared__ int wsum[4];
    const int tid = threadIdx.x, lane = tid & 63, wid = tid >> 6;
    const int i = blockIdx.x * 256 + tid;
    const int orig = (i < N_NODES) ? counts[i] : 0;
    int v = orig;
    #pragma unroll
    for (int d = 1; d < 64; d <<= 1) {
        const int u = __shfl_up(v, d);
        if (lane >= d) v += u;
    }
    if (lane == 63) wsum[wid] = v;
    __syncthreads();
    int pre = boff[blockIdx.x];
    for (int ww = 0; ww < wid; ++ww) pre += wsum[ww];
    const int excl = pre + v - orig;
    if (i < N_NODES) { offsets[i] = excl; cursor[i] = excl; }
    if (i == N_NODES - 1) offsets[N_NODES] = excl + orig;
}

// ---------------------------------------------------------------------------
// Kernel 4: bucket edges by dst: recs[pos] = (src, bits(val))
// ---------------------------------------------------------------------------
__global__ __launch_bounds__(256) void gcn_build(const int*   __restrict__ src,
                                                 const int*   __restrict__ dst,
                                                 const float* __restrict__ val,
                                                 int*  __restrict__ cursor,
                                                 int2* __restrict__ recs)
{
    const int e = blockIdx.x * 256 + threadIdx.x;
    if (e < N_EDGES) {
        const int d   = dst[e];
        const int pos = atomicAdd(&cursor[d], 1);
        recs[pos] = make_int2(src[e], __float_as_int(val[e]));
    }
}

// ---------------------------------------------------------------------------
// Kernel 5: per-node gather-accumulate, bias fused, no atomics.
// 4-deep rotating prefetch with NAMED registers (runtime-indexed arrays would
// spill to scratch — rule #20): turns ~16 serial L2/L3 round-trips per node
// into ~4. readfirstlane(n) -> offsets/recs on the scalar path.
// ---------------------------------------------------------------------------
__global__ __launch_bounds__(256) void gcn_gather(const float* __restrict__ support,
                                                  const int2*  __restrict__ recs,
                                                  const int*   __restrict__ offsets,
                                                  const float* __restrict__ bias,
                                                  float* __restrict__ out)
{
    const int lane = threadIdx.x & 63;
    const int n = __builtin_amdgcn_readfirstlane(
                      (int)((blockIdx.x * 256 + threadIdx.x) >> 6));
    if (n >= N_NODES) return;

    const float b   = bias[lane];
    const int   beg = offsets[n];
    const int   end = offsets[n + 1];
    float acc = 0.f;
    int i = beg;

    if (end - beg >= 8) {
        int2 ra = recs[i],   rb = recs[i+1], rc = recs[i+2], rd = recs[i+3];
        float sa = support[(size_t)ra.x * OUT_DIM + lane];
        float sb = support[(size_t)rb.x * OUT_DIM + lane];
        float sc = support[(size_t)rc.x * OUT_DIM + lane];
        float sd = support[(size_t)rd.x * OUT_DIM + lane];
        for (; i + 8 <= end; i += 4) {
            const int2 na = recs[i+4], nb = recs[i+5], nc = recs[i+6], nd = recs[i+7];
            const float ta = support[(size_t)na.x * OUT_DIM + lane];
            const float tb = support[(size_t)nb.x * OUT_DIM + lane];
            const float tc = support[(size_t)nc.x * OUT_DIM + lane];
            const float td = support[(size_t)nd.x * OUT_DIM + lane];
            acc += __int_as_float(ra.y) * sa;
            acc += __int_as_float(rb.y) * sb;
            acc += __int_as_float(rc.y) * sc;
            acc += __int_as_float(rd.y) * sd;
            ra = na; sa = ta;  rb = nb; sb = tb;
            rc = nc; sc = tc;  rd = nd; sd = td;
        }
        acc += __int_as_float(ra.y) * sa + __int_as_float(rb.y) * sb
             + __int_as_float(rc.y) * sc + __int_as_float(rd.y) * sd;
        i += 4;
    }
    for (; i < end; ++i) {
        const int2 r = recs[i];
        acc += __int_as_float(r.y) * support[(size_t)r.x * OUT_DIM + lane];
    }
    out[(size_t)n * OUT_DIM + lane] = acc + b;
}

// ---------------------------------------------------------------------------
extern "C" void kernel_launch(void* const* d_in, const int* in_sizes, int n_in,
                              void* d_out, int out_size, void* d_ws, size_t ws_size,
                              hipStream_t stream)
{
    const float* input  = (const float*)d_in[0];
    const float* weight = (const float*)d_in[1];
    const float* bias   = (const float*)d_in[2];
    const float* eval_  = (const float*)d_in[3];
    const int*   esrc   = (const int*)d_in[4];
    const int*   edst   = (const int*)d_in[5];
    float*       out    = (float*)d_out;

    char* ws = (char*)d_ws;
    float* support = (float*)(ws + WS_SUPPORT);
    int*   counts  = (int*)(ws + WS_COUNTS);
    int*   offsets = (int*)(ws + WS_OFFSETS);
    int*   cursor  = (int*)(ws + WS_CURSOR);
    int*   bsum    = (int*)(ws + WS_BSUM);
    int*   boff    = (int*)(ws + WS_BOFF);
    int2*  recs    = (int2*)(ws + WS_RECS);

    hipMemsetAsync(counts, 0, N_NODES * sizeof(int), stream);

    // support = X @ W
    gcn_gemm<<<(N_NODES + 63) / 64, 256, 0, stream>>>(input, weight, support);

    // CSR-by-dst build
    gcn_hist <<<(N_EDGES + 255) / 256, 256, 0, stream>>>(edst, counts);
    gcn_scanA<<<NB, 256, 0, stream>>>(counts, bsum);
    gcn_scanB<<<1, 256, 0, stream>>>(bsum, boff);
    gcn_scanC<<<NB, 256, 0, stream>>>(counts, boff, offsets, cursor);
    gcn_build<<<(N_EDGES + 255) / 256, 256, 0, stream>>>(esrc, edst, eval_, cursor, recs);

    // out[n] = sum_{e: dst=n} val_e * support[src_e] + bias
    gcn_gather<<<(N_NODES * 64) / 256, 256, 0, stream>>>(support, recs, offsets, bias, out);
}